// Round 12
// baseline (205.782 us; speedup 1.0000x reference)
//
#include <hip/hip_runtime.h>
#include <stdint.h>

typedef short short8 __attribute__((ext_vector_type(8)));
typedef short short4v __attribute__((ext_vector_type(4)));
typedef float f32x4 __attribute__((ext_vector_type(4)));
typedef unsigned short ushort_t;

// barrier with LDS-only drain (global->register prefetches stay in flight)
__device__ __forceinline__ void barrier_lds(){
  asm volatile("s_waitcnt lgkmcnt(0)\n\ts_barrier" ::: "memory");
}

__device__ __forceinline__ unsigned short bf16_rne(float x){
  unsigned int u = __float_as_uint(x);
  return (unsigned short)((u + 0x7FFFu + ((u >> 16) & 1u)) >> 16);
}
__device__ __forceinline__ unsigned cvt_pk(float a, float b){
  unsigned r;
  asm("v_cvt_pk_bf16_f32 %0, %1, %2" : "=v"(r) : "v"(a), "v"(b));
  return r;
}
__device__ __forceinline__ void split4(float a0, float a1, float a2, float a3,
                                       unsigned &h0, unsigned &h1,
                                       unsigned &l0, unsigned &l1){
  h0 = cvt_pk(a0, a1); h1 = cvt_pk(a2, a3);
  float f0 = __uint_as_float(h0 << 16), f1 = __uint_as_float(h0 & 0xFFFF0000u);
  float f2 = __uint_as_float(h1 << 16), f3 = __uint_as_float(h1 & 0xFFFF0000u);
  l0 = cvt_pk(a0 - f0, a1 - f1); l1 = cvt_pk(a2 - f2, a3 - f3);
}
__device__ __forceinline__ uint4 hi8(float4 x, float4 y){
  uint4 h; h.x = cvt_pk(x.x, x.y); h.y = cvt_pk(x.z, x.w);
  h.z = cvt_pk(y.x, y.y); h.w = cvt_pk(y.z, y.w); return h;
}
__device__ __forceinline__ void split8(float4 x, float4 y, uint4 &h, uint4 &l){
  split4(x.x, x.y, x.z, x.w, h.x, h.y, l.x, l.y);
  split4(y.x, y.y, y.z, y.w, h.z, h.w, l.z, l.w);
}
__device__ __forceinline__ short8 comb(short4v a, short4v b){
  short8 r; r[0]=a[0]; r[1]=a[1]; r[2]=a[2]; r[3]=a[3];
  r[4]=b[0]; r[5]=b[1]; r[6]=b[2]; r[7]=b[3]; return r;
}

// ---------------- generic bt-GEMM (BK=64, two register sets) ----------------
// C[m][n] = sum_k A[m][k]*B[n][k], both row-major.
// TS: output tile. ABF/BBF: operand bf16 (1) or f32 fused-convert (0).
// NT=3: Markidis 3-term. EPI=1: +cvec[row]. OB=1: bf16 out.
template<int TS, int ABF, int BBF, int NT, int EPI, int OB>
__global__ __launch_bounds__(256, 2) void gemm_bt(
    const void* __restrict__ Av, const void* __restrict__ Bv,
    void* __restrict__ Cv, const float* __restrict__ cvec,
    int tn, int K, int lda, int ldb, int ldc,
    long sA, long sB, long sC, long scv)
{
  const int bz = blockIdx.y;
  const int mt = blockIdx.x / tn, nt = blockIdx.x % tn;
  const int m0 = mt * TS, n0 = nt * TS;

  constexpr int MI   = TS / 64;
  constexpr int ROWE = TS * 32;                      // shorts per 32-K plane
  constexpr int PL   = (NT == 3) ? 2 * ROWE : ROWE;  // shorts per sub per tensor
  constexpr int TBYT = 4 * PL;                       // bytes per tensor (2 subs)
  constexpr int SB   = (2 * TBYT > 16384) ? 2 * TBYT : 16384;
  constexpr int EL   = (TS == 128) ? 16 : 8;
  __shared__ __align__(16) char SMEM[SB];
  short* Ah  = (short*)SMEM;
  short* Bh2 = (short*)(SMEM + TBYT);
  float* EP  = (float*)SMEM;

  const int t = threadIdx.x;
  const int lane = t & 63, wid = t >> 6;
  const int rowS = (TS == 128) ? (t >> 1) : (t >> 2);
  const int kh   = (TS == 128) ? (t & 1)  : (t & 3);
  const int wr = wid >> 1, wc = wid & 1;
  const int fr = lane & 15, fg = lane >> 4;

  f32x4 acc[2*MI][2*MI];
  const f32x4 Z = {0.f, 0.f, 0.f, 0.f};
  #pragma unroll
  for (int i = 0; i < 2*MI; i++)
    #pragma unroll
    for (int j = 0; j < 2*MI; j++) acc[i][j] = Z;

  const int wbase = rowS * 32;
  const int sw = (rowS >> 1) & 3;
  const int i0 = wbase + ((((TS == 128) ? (kh << 1) : kh) ^ sw) << 3);
  const int i1 = (TS == 128) ? (wbase + ((((kh << 1) + 1) ^ sw) << 3)) : 0;

  const float*    Afp = (const float*)Av    + sA * bz + (long)(m0 + rowS) * lda + kh * EL;
  const ushort_t* Abp = (const ushort_t*)Av + sA * bz + (long)(m0 + rowS) * lda + kh * EL;
  const float*    Bfp = (const float*)Bv    + sB * bz + (long)(n0 + rowS) * ldb + kh * EL;
  const ushort_t* Bbp = (const ushort_t*)Bv + sB * bz + (long)(n0 + rowS) * ldb + kh * EL;

  struct Pf { float4 v[4]; };
  struct Ps { short8 v[2]; };
  Pf Af[2], Bf[2]; Ps As8[2], Bs8[2];

  auto loadA = [&](int s, int kk){
    if (ABF == 0){
      const float4* p = (const float4*)(Afp + kk);
      Af[s].v[0] = p[0]; Af[s].v[1] = p[1];
      if (TS == 128){ Af[s].v[2] = p[2]; Af[s].v[3] = p[3]; }
    } else {
      const short8* p = (const short8*)(Abp + kk);
      As8[s].v[0] = p[0]; if (TS == 128) As8[s].v[1] = p[1];
    }
  };
  auto loadB = [&](int s, int kk){
    if (BBF == 0){
      const float4* p = (const float4*)(Bfp + kk);
      Bf[s].v[0] = p[0]; Bf[s].v[1] = p[1];
      if (TS == 128){ Bf[s].v[2] = p[2]; Bf[s].v[3] = p[3]; }
    } else {
      const short8* p = (const short8*)(Bbp + kk);
      Bs8[s].v[0] = p[0]; if (TS == 128) Bs8[s].v[1] = p[1];
    }
  };

  auto stage = [&](int s){
    const int off = s * PL;
    if (ABF == 0){
      if (NT == 3){
        uint4 h0, l0; split8(Af[s].v[0], Af[s].v[1], h0, l0);
        *(uint4*)&Ah[off + i0] = h0; *(uint4*)&Ah[off + i0 + ROWE] = l0;
        if (TS == 128){
          uint4 h1, l1; split8(Af[s].v[2], Af[s].v[3], h1, l1);
          *(uint4*)&Ah[off + i1] = h1; *(uint4*)&Ah[off + i1 + ROWE] = l1;
        }
      } else {
        *(uint4*)&Ah[off + i0] = hi8(Af[s].v[0], Af[s].v[1]);
        if (TS == 128) *(uint4*)&Ah[off + i1] = hi8(Af[s].v[2], Af[s].v[3]);
      }
    } else {
      *(short8*)&Ah[off + i0] = As8[s].v[0];
      if (TS == 128) *(short8*)&Ah[off + i1] = As8[s].v[1];
    }
    if (BBF == 0){
      if (NT == 3){
        uint4 h0, l0; split8(Bf[s].v[0], Bf[s].v[1], h0, l0);
        *(uint4*)&Bh2[off + i0] = h0; *(uint4*)&Bh2[off + i0 + ROWE] = l0;
        if (TS == 128){
          uint4 h1, l1; split8(Bf[s].v[2], Bf[s].v[3], h1, l1);
          *(uint4*)&Bh2[off + i1] = h1; *(uint4*)&Bh2[off + i1 + ROWE] = l1;
        }
      } else {
        *(uint4*)&Bh2[off + i0] = hi8(Bf[s].v[0], Bf[s].v[1]);
        if (TS == 128) *(uint4*)&Bh2[off + i1] = hi8(Bf[s].v[2], Bf[s].v[3]);
      }
    } else {
      *(short8*)&Bh2[off + i0] = Bs8[s].v[0];
      if (TS == 128) *(short8*)&Bh2[off + i1] = Bs8[s].v[1];
    }
  };

  loadA(0, 0); loadB(0, 0); loadA(1, 32); loadB(1, 32);

  for (int k0 = 0; k0 < K; k0 += 64){
    barrier_lds();
    stage(0);
    { int kn = (k0 + 64 < K) ? (k0 + 64) : k0;       loadA(0, kn); loadB(0, kn); }
    stage(1);
    { int kn = (k0 + 64 < K) ? (k0 + 96) : (k0 + 32); loadA(1, kn); loadB(1, kn); }
    barrier_lds();

    #pragma unroll
    for (int s = 0; s < 2; s++){
      const int off = s * PL;
      short8 fa[2*MI], fb[2*MI], fal[2*MI], fbl[2*MI];
      #pragma unroll
      for (int mi = 0; mi < 2*MI; mi++){
        int r = wr * (32*MI) + mi * 16 + fr;
        int idx = off + r * 32 + ((fg ^ ((r >> 1) & 3)) << 3);
        fa[mi] = *(const short8*)&Ah[idx];
        if (NT == 3) fal[mi] = *(const short8*)&Ah[idx + ROWE];
      }
      #pragma unroll
      for (int ni = 0; ni < 2*MI; ni++){
        int r = wc * (32*MI) + ni * 16 + fr;
        int idx = off + r * 32 + ((fg ^ ((r >> 1) & 3)) << 3);
        fb[ni] = *(const short8*)&Bh2[idx];
        if (NT == 3) fbl[ni] = *(const short8*)&Bh2[idx + ROWE];
      }
      #pragma unroll
      for (int mi = 0; mi < 2*MI; mi++)
        #pragma unroll
        for (int ni = 0; ni < 2*MI; ni++){
          acc[mi][ni] = __builtin_amdgcn_mfma_f32_16x16x32_bf16(fa[mi], fb[ni], acc[mi][ni], 0, 0, 0);
          if (NT == 3){
            acc[mi][ni] = __builtin_amdgcn_mfma_f32_16x16x32_bf16(fal[mi], fb[ni],  acc[mi][ni], 0, 0, 0);
            acc[mi][ni] = __builtin_amdgcn_mfma_f32_16x16x32_bf16(fa[mi],  fbl[ni], acc[mi][ni], 0, 0, 0);
          }
        }
    }
  }

  // ---- coalesced epilogue via LDS restage ----
  float*    Cf = (float*)Cv    + sC * bz;
  ushort_t* Cb = (ushort_t*)Cv + sC * bz;
  if (TS == 128){
    #pragma unroll
    for (int p = 0; p < 4; p++){
      __syncthreads();
      if (wr == (p >> 1)){
        #pragma unroll
        for (int m2 = 0; m2 < 2; m2++){
          int mi = 2 * (p & 1) + m2;
          #pragma unroll
          for (int ni = 0; ni < 4; ni++)
            #pragma unroll
            for (int j = 0; j < 4; j++){
              int lr = m2 * 16 + fg * 4 + j;
              float o = acc[mi][ni][j];
              if (EPI == 1) o += cvec[scv * bz + m0 + p * 32 + lr];
              EP[lr * 128 + wc * 64 + ni * 16 + fr] = o;
            }
        }
      }
      __syncthreads();
      const int row = t >> 3, seg = t & 7;
      const float* src = EP + row * 128 + seg * 16;
      if (OB == 1){
        ushort_t* dst = Cb + (long)(m0 + p * 32 + row) * ldc + n0 + seg * 16;
        uint4 o0, o1;
        o0.x = cvt_pk(src[0], src[1]);  o0.y = cvt_pk(src[2], src[3]);
        o0.z = cvt_pk(src[4], src[5]);  o0.w = cvt_pk(src[6], src[7]);
        o1.x = cvt_pk(src[8], src[9]);  o1.y = cvt_pk(src[10], src[11]);
        o1.z = cvt_pk(src[12], src[13]); o1.w = cvt_pk(src[14], src[15]);
        *(uint4*)dst = o0; *(uint4*)(dst + 8) = o1;
      } else {
        float* dst = Cf + (long)(m0 + p * 32 + row) * ldc + n0 + seg * 16;
        #pragma unroll
        for (int c = 0; c < 4; c++)
          *(float4*)(dst + c * 4) = *(const float4*)(src + c * 4);
      }
    }
  } else {
    __syncthreads();
    #pragma unroll
    for (int mi = 0; mi < 2; mi++)
      #pragma unroll
      for (int ni = 0; ni < 2; ni++)
        #pragma unroll
        for (int j = 0; j < 4; j++){
          int lr = wr * 32 + mi * 16 + fg * 4 + j;
          float o = acc[mi][ni][j];
          if (EPI == 1) o += cvec[scv * bz + m0 + lr];
          EP[lr * 64 + wc * 32 + ni * 16 + fr] = o;
        }
    __syncthreads();
    const int row = t >> 2, seg = t & 3;
    const float* src = EP + row * 64 + seg * 16;
    if (OB == 1){
      ushort_t* dst = Cb + (long)(m0 + row) * ldc + n0 + seg * 16;
      uint4 o0, o1;
      o0.x = cvt_pk(src[0], src[1]);  o0.y = cvt_pk(src[2], src[3]);
      o0.z = cvt_pk(src[4], src[5]);  o0.w = cvt_pk(src[6], src[7]);
      o1.x = cvt_pk(src[8], src[9]);  o1.y = cvt_pk(src[10], src[11]);
      o1.z = cvt_pk(src[12], src[13]); o1.w = cvt_pk(src[14], src[15]);
      *(uint4*)dst = o0; *(uint4*)(dst + 8) = o1;
    } else {
      float* dst = Cf + (long)(m0 + row) * ldc + n0 + seg * 16;
      #pragma unroll
      for (int c = 0; c < 4; c++)
        *(float4*)(dst + c * 4) = *(const float4*)(src + c * 4);
    }
  }
}

// ---------------- GEMM1: Mt[b][kc][qc] = sum_s k[b][s][kc]*q[b][s][qc] ------
// 2-TERM split: k = hi+lo, q = hi only (absmax 0.039 < 0.0906 budget).
// NSP=8 (2 blocks/CU; NSP=4 = 1 block/CU loses barrier overlap, R10).
// launch_bounds (256,2): (256,4) caps VGPR at 64 -> spills (R5).
template<int NSP>
__global__ __launch_bounds__(256, 2) void gemm1_tn(
    const float* __restrict__ q, const float* __restrict__ k,
    float* __restrict__ mtp, float* __restrict__ sqp, float* __restrict__ skp)
{
  constexpr int CH = 8192 / NSP;
  constexpr int STEPS = CH / 64;
  const int b = blockIdx.z, sp = blockIdx.y;
  const int mt = blockIdx.x >> 2, nt = blockIdx.x & 3;
  const float* qb = q + (long)b * 8192 * 512;
  const float* kb = k + (long)b * 8192 * 512;

  __shared__ __align__(16) char SMEM[65536];
  unsigned char* As = (unsigned char*)SMEM;            // k: hi+lo, 16KB/sub
  unsigned char* Bs = (unsigned char*)(SMEM + 32768);  // q: hi only

  const int t = threadIdx.x;
  const int lam = t & 31, sg = t >> 5;
  const int lane = t & 63, wid = t >> 6;
  const int wr = wid >> 1, wc = wid & 1;
  const int fr = lane & 15, fg = lane >> 4;

  f32x4 acc[4][4];
  const f32x4 Z = {0.f, 0.f, 0.f, 0.f};
  #pragma unroll
  for (int i = 0; i < 4; i++)
    #pragma unroll
    for (int j = 0; j < 4; j++) acc[i][j] = Z;

  float sumk4[4] = {0.f, 0.f, 0.f, 0.f};
  float sumq4[4] = {0.f, 0.f, 0.f, 0.f};

  int wA[4];
  #pragma unroll
  for (int j = 0; j < 4; j++){
    int c = lam * 4 + j;
    int swc = ((c >> 2) ^ ((c & 3) << 1)) & 7;
    wA[j] = c * 128 + ((sg ^ swc) << 4);
  }

  const float* kbase = kb + (long)(sp * CH + sg * 4) * 512 + mt * 128 + lam * 4;
  const float* qbase = qb + (long)(sp * CH + sg * 4) * 512 + nt * 128 + lam * 4;

  struct Pf { float4 v[4]; };
  Pf Kf[2], Qf[2];

  auto ldK = [&](int s, int st){
    const float* p = kbase + (long)(st * 64 + s * 32) * 512;
    Kf[s].v[0] = *(const float4*)(p);
    Kf[s].v[1] = *(const float4*)(p + 512);
    Kf[s].v[2] = *(const float4*)(p + 1024);
    Kf[s].v[3] = *(const float4*)(p + 1536);
  };
  auto ldQ = [&](int s, int st){
    const float* p = qbase + (long)(st * 64 + s * 32) * 512;
    Qf[s].v[0] = *(const float4*)(p);
    Qf[s].v[1] = *(const float4*)(p + 512);
    Qf[s].v[2] = *(const float4*)(p + 1024);
    Qf[s].v[3] = *(const float4*)(p + 1536);
  };

  auto cvK = [&](int s){
    #pragma unroll
    for (int j = 0; j < 4; j++){
      float a0 = ((const float*)&Kf[s].v[0])[j], a1 = ((const float*)&Kf[s].v[1])[j];
      float a2 = ((const float*)&Kf[s].v[2])[j], a3 = ((const float*)&Kf[s].v[3])[j];
      sumk4[j] += (a0 + a1) + (a2 + a3);
      unsigned h0, h1, l0, l1;
      split4(a0, a1, a2, a3, h0, h1, l0, l1);
      uint4 w; w.x = h0; w.y = h1; w.z = l0; w.w = l1;
      *(uint4*)(As + s * 16384 + wA[j]) = w;
    }
  };
  auto cvQ = [&](int s){   // hi only
    #pragma unroll
    for (int j = 0; j < 4; j++){
      float a0 = ((const float*)&Qf[s].v[0])[j], a1 = ((const float*)&Qf[s].v[1])[j];
      float a2 = ((const float*)&Qf[s].v[2])[j], a3 = ((const float*)&Qf[s].v[3])[j];
      sumq4[j] += (a0 + a1) + (a2 + a3);
      uint2 w2; w2.x = cvt_pk(a0, a1); w2.y = cvt_pk(a2, a3);
      *(uint2*)(Bs + s * 16384 + wA[j]) = w2;
    }
  };

  ldK(0, 0); ldQ(0, 0); ldK(1, 0); ldQ(1, 0);

  for (int st = 0; st < STEPS; ++st){
    barrier_lds();
    cvK(0); cvQ(0);
    { int ns = (st < STEPS - 1) ? (st + 1) : st; ldK(0, ns); ldQ(0, ns); }
    cvK(1); cvQ(1);
    { int ns = (st < STEPS - 1) ? (st + 1) : st; ldK(1, ns); ldQ(1, ns); }
    barrier_lds();

    #pragma unroll
    for (int s = 0; s < 2; s++){
      const unsigned char* Ab = As + s * 16384;
      const unsigned char* Bb = Bs + s * 16384;
      short8 fa[4], fal[4], fb[4];
      #pragma unroll
      for (int mi = 0; mi < 4; mi++){
        int r = wr * 64 + mi * 16 + fr;
        int swc = ((r >> 2) ^ ((r & 3) << 1)) & 7;
        const unsigned char* bp = Ab + r * 128;
        int u0 = (((fg << 1) + 0) ^ swc) << 4;
        int u1 = (((fg << 1) + 1) ^ swc) << 4;
        fa[mi]  = comb(*(const short4v*)(bp + u0),     *(const short4v*)(bp + u1));
        fal[mi] = comb(*(const short4v*)(bp + u0 + 8), *(const short4v*)(bp + u1 + 8));
      }
      #pragma unroll
      for (int ni = 0; ni < 4; ni++){
        int r = wc * 64 + ni * 16 + fr;
        int swc = ((r >> 2) ^ ((r & 3) << 1)) & 7;
        const unsigned char* bp = Bb + r * 128;
        int u0 = (((fg << 1) + 0) ^ swc) << 4;
        int u1 = (((fg << 1) + 1) ^ swc) << 4;
        fb[ni]  = comb(*(const short4v*)(bp + u0), *(const short4v*)(bp + u1));
      }
      #pragma unroll
      for (int mi = 0; mi < 4; mi++)
        #pragma unroll
        for (int ni = 0; ni < 4; ni++){
          acc[mi][ni] = __builtin_amdgcn_mfma_f32_16x16x32_bf16(fa[mi],  fb[ni], acc[mi][ni], 0, 0, 0);
          acc[mi][ni] = __builtin_amdgcn_mfma_f32_16x16x32_bf16(fal[mi], fb[ni], acc[mi][ni], 0, 0, 0);
        }
    }
  }

  float* Cp = mtp + ((long)sp * 4 + b) * (512 * 512);
  #pragma unroll
  for (int mi = 0; mi < 4; mi++)
    #pragma unroll
    for (int ni = 0; ni < 4; ni++){
      int gr0 = mt * 128 + wr * 64 + mi * 16 + fg * 4;
      int gc  = nt * 128 + wc * 64 + ni * 16 + fr;
      #pragma unroll
      for (int j = 0; j < 4; j++)
        Cp[(long)(gr0 + j) * 512 + gc] = acc[mi][ni][j];
    }

  __syncthreads();
  float* red = (float*)SMEM;
  if (mt == 0){
    #pragma unroll
    for (int j = 0; j < 4; j++) red[sg * 128 + lam * 4 + j] = sumq4[j];
    __syncthreads();
    if (t < 128){
      float s2 = 0.f;
      #pragma unroll
      for (int gg = 0; gg < 8; gg++) s2 += red[gg * 128 + t];
      sqp[((long)b * NSP + sp) * 512 + nt * 128 + t] = s2;
    }
    __syncthreads();
  }
  if (nt == 0){
    #pragma unroll
    for (int j = 0; j < 4; j++) red[sg * 128 + lam * 4 + j] = sumk4[j];
    __syncthreads();
    if (t < 128){
      float s2 = 0.f;
      #pragma unroll
      for (int gg = 0; gg < 8; gg++) s2 += red[gg * 128 + t];
      skp[((long)b * NSP + sp) * 512 + mt * 128 + t] = s2;
    }
  }
}

// ---------------- midprep: reduceM + transpose512 + smallprep fused ---------
// bid <1024: in-place reduce of NS slices into slice 0
// bid 1024..1279: Wv transpose -> wvT
// bid 1280..1311: wqsq/wksk dot products
template<int NS>
__global__ __launch_bounds__(256) void midprep(
    float* __restrict__ p,
    const float* __restrict__ Wv, float* __restrict__ wvT,
    const float* __restrict__ sqp, const float* __restrict__ skp,
    const float* __restrict__ Wq, const float* __restrict__ Wk,
    float* __restrict__ wqsq, float* __restrict__ wksk)
{
  __shared__ float shm[33 * 32];
  const int bid = blockIdx.x;
  const int t = threadIdx.x;
  if (bid < 1024){
    const int b = bid >> 8;
    const long i = (long)(bid & 255) * 1024 + t * 4;
    float4 s = {0.f, 0.f, 0.f, 0.f};
    #pragma unroll
    for (int j = 0; j < NS; j++){
      float4 v = *(const float4*)(p + ((long)j * 4 + b) * 262144 + i);
      s.x += v.x; s.y += v.y; s.z += v.z; s.w += v.w;
    }
    *(float4*)(p + (long)b * 262144 + i) = s;
  } else if (bid < 1280){
    const int bb = bid - 1024;
    const int bx = bb & 15, by = bb >> 4;
    const int tx = t & 31, ty = t >> 5;
    float (*tile)[33] = (float(*)[33])shm;
    #pragma unroll
    for (int r = 0; r < 4; r++)
      tile[ty + 8*r][tx] = Wv[(long)(by*32 + ty + 8*r) * 512 + bx*32 + tx];
    __syncthreads();
    #pragma unroll
    for (int r = 0; r < 4; r++)
      wvT[(long)(bx*32 + ty + 8*r) * 512 + by*32 + tx] = tile[tx][ty + 8*r];
  } else {
    const int bb = bid - 1280;
    const int tau = bb >> 4;
    const int b = (bb >> 2) & 3, ab = bb & 3;
    const float* P = tau ? skp : sqp;
    const float* W = tau ? Wk : Wq;
    float* O = tau ? wksk : wqsq;
    float* sv = shm;
    for (int i = t; i < 512; i += 256){
      float s = 0.f;
      #pragma unroll
      for (int g = 0; g < NS; g++) s += P[((long)b * NS + g) * 512 + i];
      sv[i] = s;
    }
    __syncthreads();
    const int a = ab * 128 + (t >> 1), half = t & 1;
    const float* Wr = W + (long)a * 512 + half * 256;
    const float* sp2 = sv + half * 256;
    float d = 0.f;
    #pragma unroll 8
    for (int j = 0; j < 256; j++) d += Wr[j] * sp2[j];
    d += __shfl_xor(d, 1);
    if (!half) O[(long)b * 512 + a] = d;
  }
}

// ---------------- a2_fused: softmax + A2 GEMM in one kernel -----------------
// Per 64x64 tile of A2: recompute softmax of the 64 owned rows (unnormalized
// e = exp(l-m) stored as bf16 in the MFMA A-fragment layout in LDS), run the
// K=512 loop against staged WvT, normalize by 1/rowsum in the epilogue.
// cv[a] = (sum_c e*bv)/rowsum written by nt==0 blocks. a2 output bf16.
__global__ __launch_bounds__(256, 2) void a2_fused(
    const float* __restrict__ num, const float* __restrict__ wvT,
    ushort_t* __restrict__ a2h, float* __restrict__ cv,
    const float* __restrict__ wqsq, const float* __restrict__ wksk,
    const float* __restrict__ bq, const float* __restrict__ bk,
    const float* __restrict__ bv, const int* __restrict__ gt)
{
  const int b = blockIdx.y;
  const int mt = blockIdx.x >> 3, nt = blockIdx.x & 7;
  const int a0 = mt * 64, n0 = nt * 64;

  __shared__ __align__(16) short Pl[16 * 2048];   // 64KB: 16 subs x [64 rows][32 k]
  __shared__ __align__(16) short Bh2[2 * 2048];   // 8KB
  __shared__ unsigned char gf[512];
  __shared__ unsigned gfb[16];
  __shared__ float sarr[64], cvarr[64];

  const int t = threadIdx.x;
  const int lane = t & 63, wid = t >> 6;
  const int wr = wid >> 1, wc = wid & 1;
  const int fr = lane & 15, fg = lane >> 4;

  gf[t] = 0; gf[t + 256] = 0;
  __syncthreads();
  if (t < 64) gf[gt[t]] = 1;
  __syncthreads();
  if (t < 16){
    unsigned m2 = 0;
    #pragma unroll
    for (int j = 0; j < 32; j++) m2 |= ((unsigned)gf[t * 32 + j]) << j;
    gfb[t] = m2;
  }
  __syncthreads();

  // ---- softmax: row = t>>2 (local), cols (t&3)*128..+128 ----
  const int row = t >> 2;
  const int a = a0 + row;
  const int cs = (t & 3) * 128;
  const float* nrow = num + ((long)b * 512 + a) * 512;
  const float* wkrow = wksk + b * 512;
  const float bqa = bq[a], wqa = wqsq[b * 512 + a];
  const bool maskable = (gf[a] == 0);
  unsigned gm[4];
  #pragma unroll
  for (int j = 0; j < 4; j++) gm[j] = gfb[(cs >> 5) + j];
  const float SCL = 0.04419417382415922f;

  // pass 1: row max
  float m = -1e30f;
  for (int c8 = cs; c8 < cs + 128; c8 += 8){
    float4 nv0 = *(const float4*)(nrow + c8),  nv1 = *(const float4*)(nrow + c8 + 4);
    float4 bk0 = *(const float4*)(bk + c8),    bk1 = *(const float4*)(bk + c8 + 4);
    float4 wk0 = *(const float4*)(wkrow + c8), wk1 = *(const float4*)(wkrow + c8 + 4);
    #pragma unroll
    for (int j = 0; j < 8; j++){
      int c = c8 + j;
      float nvv = (j < 4) ? ((const float*)&nv0)[j] : ((const float*)&nv1)[j-4];
      float bkv = (j < 4) ? ((const float*)&bk0)[j] : ((const float*)&bk1)[j-4];
      float wkv = (j < 4) ? ((const float*)&wk0)[j] : ((const float*)&wk1)[j-4];
      float l = (nvv + wqa * bkv + bqa * wkv + 8192.0f * bqa * bkv) * SCL;
      bool msk = (a < c) && maskable && !((gm[(c - cs) >> 5] >> (c & 31)) & 1u);
      if (msk) l = -1e30f;
      m = fmaxf(m, l);
    }
  }
  m = fmaxf(m, __shfl_xor(m, 1));
  m = fmaxf(m, __shfl_xor(m, 2));

  // pass 2: e = exp(l-m); sum, cv-partial, write bf16 e into fragment layout
  float ssum = 0.f, cpart = 0.f;
  for (int c8 = cs; c8 < cs + 128; c8 += 8){
    float4 nv0 = *(const float4*)(nrow + c8),  nv1 = *(const float4*)(nrow + c8 + 4);
    float4 bk0 = *(const float4*)(bk + c8),    bk1 = *(const float4*)(bk + c8 + 4);
    float4 wk0 = *(const float4*)(wkrow + c8), wk1 = *(const float4*)(wkrow + c8 + 4);
    float4 bv0 = *(const float4*)(bv + c8),    bv1 = *(const float4*)(bv + c8 + 4);
    float e[8];
    #pragma unroll
    for (int j = 0; j < 8; j++){
      int c = c8 + j;
      float nvv = (j < 4) ? ((const float*)&nv0)[j] : ((const float*)&nv1)[j-4];
      float bkv = (j < 4) ? ((const float*)&bk0)[j] : ((const float*)&bk1)[j-4];
      float wkv = (j < 4) ? ((const float*)&wk0)[j] : ((const float*)&wk1)[j-4];
      float bvv = (j < 4) ? ((const float*)&bv0)[j] : ((const float*)&bv1)[j-4];
      float l = (nvv + wqa * bkv + bqa * wkv + 8192.0f * bqa * bkv) * SCL;
      bool msk = (a < c) && maskable && !((gm[(c - cs) >> 5] >> (c & 31)) & 1u);
      if (msk) l = -1e30f;
      float ev = __expf(l - m);
      e[j] = ev; ssum += ev; cpart += ev * bvv;
    }
    const int sub = c8 >> 5;
    const int slot = ((c8 & 31) >> 3) ^ ((row >> 1) & 3);
    uint4 w4;
    w4.x = cvt_pk(e[0], e[1]); w4.y = cvt_pk(e[2], e[3]);
    w4.z = cvt_pk(e[4], e[5]); w4.w = cvt_pk(e[6], e[7]);
    *(uint4*)&Pl[sub * 2048 + row * 32 + slot * 8] = w4;
  }
  ssum  += __shfl_xor(ssum, 1);  ssum  += __shfl_xor(ssum, 2);
  cpart += __shfl_xor(cpart, 1); cpart += __shfl_xor(cpart, 2);
  if ((t & 3) == 0){ sarr[row] = ssum; cvarr[row] = cpart; }
  __syncthreads();
  if (nt == 0 && t < 64) cv[(long)b * 512 + a0 + t] = cvarr[t] / sarr[t];

  // ---- GEMM phase: acc += P (resident) x WvT (staged) ----
  f32x4 acc[2][2];
  const f32x4 Z = {0.f, 0.f, 0.f, 0.f};
  acc[0][0] = Z; acc[0][1] = Z; acc[1][0] = Z; acc[1][1] = Z;

  const int rowS = t >> 2, kh = t & 3;
  const int ib = rowS * 32 + ((kh ^ ((rowS >> 1) & 3)) << 3);
  const float* Bfp = wvT + (long)(n0 + rowS) * 512 + kh * 8;

  struct Pf2 { float4 v[2]; };
  Pf2 Bf[2];
  auto ldB = [&](int s, int kk){
    const float4* p = (const float4*)(Bfp + kk);
    Bf[s].v[0] = p[0]; Bf[s].v[1] = p[1];
  };
  auto stB = [&](int s){
    *(uint4*)&Bh2[s * 2048 + ib] = hi8(Bf[s].v[0], Bf[s].v[1]);
  };

  ldB(0, 0); ldB(1, 32);

  for (int k0 = 0; k0 < 512; k0 += 64){
    barrier_lds();
    stB(0);
    { int kn = (k0 + 64 < 512) ? (k0 + 64) : k0;        ldB(0, kn); }
    stB(1);
    { int kn = (k0 + 64 < 512) ? (k0 + 96) : (k0 + 32); ldB(1, kn); }
    barrier_lds();

    #pragma unroll
    for (int s = 0; s < 2; s++){
      const int sub = (k0 >> 5) + s;
      short8 fa[2], fb[2];
      #pragma unroll
      for (int mi = 0; mi < 2; mi++){
        int r = wr * 32 + mi * 16 + fr;
        fa[mi] = *(const short8*)&Pl[sub * 2048 + r * 32 + ((fg ^ ((r >> 1) & 3)) << 3)];
      }
      #pragma unroll
      for (int ni = 0; ni < 2; ni++){
        int r = wc * 32 + ni * 16 + fr;
        fb[ni] = *(const short8*)&Bh2[s * 2048 + r * 32 + ((fg ^ ((r >> 1) & 3)) << 3)];
      }
      #pragma unroll
      for (int mi = 0; mi < 2; mi++)
        #pragma unroll
        for (int ni = 0; ni < 2; ni++)
          acc[mi][ni] = __builtin_amdgcn_mfma_f32_16x16x32_bf16(fa[mi], fb[ni], acc[mi][ni], 0, 0, 0);
    }
  }

  // epilogue: normalize by 1/rowsum, write bf16
  #pragma unroll
  for (int mi = 0; mi < 2; mi++)
    #pragma unroll
    for (int ni = 0; ni < 2; ni++){
      int lr0 = wr * 32 + mi * 16 + fg * 4;
      int gc  = n0 + wc * 32 + ni * 16 + fr;
      #pragma unroll
      for (int j = 0; j < 4; j++){
        float o = acc[mi][ni][j] / sarr[lr0 + j];
        a2h[(long)b * 262144 + (long)(a0 + lr0 + j) * 512 + gc] = bf16_rne(o);
      }
    }
}

// ---------------- launch -----------------------------------------------------
extern "C" void kernel_launch(void* const* d_in, const int* in_sizes, int n_in,
                              void* d_out, int out_size, void* d_ws, size_t ws_size,
                              hipStream_t stream) {
  const float* q  = (const float*)d_in[0];
  const float* k  = (const float*)d_in[1];
  const float* v  = (const float*)d_in[2];
  const float* Wq = (const float*)d_in[3];
  const float* bq = (const float*)d_in[4];
  const float* Wk = (const float*)d_in[5];
  const float* bk = (const float*)d_in[6];
  const float* Wv = (const float*)d_in[7];
  const float* bv = (const float*)d_in[8];
  const int*   gt = (const int*)d_in[9];
  float* out = (float*)d_out;

  float* w = (float*)d_ws;
  float* MT   = w;                          // slice 0 after in-place reduce
  float* T1   = w + 1048576;
  float* NUM  = w + 2097152;
  float* A2H  = w + 4194304;                // 524288 f32 = 1M ushorts
  float* WVT  = A2H + 524288;               // 262144
  float* SM   = w + 8L * 1048576;           // smalls past slice region
  float* SQP  = SM;
  float* SKP  = SQP + 32768;
  float* WQS  = SKP + 32768;
  float* WKS  = WQS + 2048;
  float* CV   = WKS + 2048;
  ushort_t* a2h = (ushort_t*)A2H;

  gemm1_tn<8><<<dim3(16, 8, 4), 256, 0, stream>>>(q, k, w, SQP, SKP);
  midprep<8><<<1312, 256, 0, stream>>>(w, Wv, WVT, SQP, SKP, Wq, Wk, WQS, WKS);
  // T1[a][j] = sum_i Wq[a][i] * MT[j][i]
  gemm_bt<64,0,0,3,0,0><<<dim3(64, 4), 256, 0, stream>>>(Wq, MT, T1, nullptr,
      8, 512, 512, 512, 512, 0L, 262144L, 262144L, 0L);
  // NUM[a][c] = sum_j T1[a][j] * Wk[c][j]
  gemm_bt<64,0,0,3,0,0><<<dim3(64, 4), 256, 0, stream>>>(T1, Wk, NUM, nullptr,
      8, 512, 512, 512, 512, 262144L, 0L, 262144L, 0L);
  // softmax + A2 fused -> bf16 a2h, cv
  a2_fused<<<dim3(64, 4), 256, 0, stream>>>(NUM, WVT, a2h, CV,
      WQS, WKS, bq, bk, bv, gt);
  // out[a][s] = sum_i A2[a][i] * v[s][i] + cv[a]   (A bf16)
  gemm_bt<128,1,0,1,1,0><<<dim3(256, 4), 256, 0, stream>>>(a2h, v, out, CV,
      64, 512, 512, 512, 8192, 262144L, 4194304L, 4194304L, 512L);
}

// Round 13
// 188.323 us; speedup vs baseline: 1.0927x; 1.0927x over previous
//
#include <hip/hip_runtime.h>
#include <stdint.h>

typedef short short8 __attribute__((ext_vector_type(8)));
typedef short short4v __attribute__((ext_vector_type(4)));
typedef float f32x4 __attribute__((ext_vector_type(4)));
typedef unsigned short ushort_t;

// barrier with LDS-only drain (global->register prefetches stay in flight)
__device__ __forceinline__ void barrier_lds(){
  asm volatile("s_waitcnt lgkmcnt(0)\n\ts_barrier" ::: "memory");
}

__device__ __forceinline__ unsigned short bf16_rne(float x){
  unsigned int u = __float_as_uint(x);
  return (unsigned short)((u + 0x7FFFu + ((u >> 16) & 1u)) >> 16);
}
__device__ __forceinline__ unsigned cvt_pk(float a, float b){
  unsigned r;
  asm("v_cvt_pk_bf16_f32 %0, %1, %2" : "=v"(r) : "v"(a), "v"(b));
  return r;
}
__device__ __forceinline__ void split4(float a0, float a1, float a2, float a3,
                                       unsigned &h0, unsigned &h1,
                                       unsigned &l0, unsigned &l1){
  h0 = cvt_pk(a0, a1); h1 = cvt_pk(a2, a3);
  float f0 = __uint_as_float(h0 << 16), f1 = __uint_as_float(h0 & 0xFFFF0000u);
  float f2 = __uint_as_float(h1 << 16), f3 = __uint_as_float(h1 & 0xFFFF0000u);
  l0 = cvt_pk(a0 - f0, a1 - f1); l1 = cvt_pk(a2 - f2, a3 - f3);
}
__device__ __forceinline__ uint4 hi8(float4 x, float4 y){
  uint4 h; h.x = cvt_pk(x.x, x.y); h.y = cvt_pk(x.z, x.w);
  h.z = cvt_pk(y.x, y.y); h.w = cvt_pk(y.z, y.w); return h;
}
__device__ __forceinline__ void split8(float4 x, float4 y, uint4 &h, uint4 &l){
  split4(x.x, x.y, x.z, x.w, h.x, h.y, l.x, l.y);
  split4(y.x, y.y, y.z, y.w, h.z, h.w, l.z, l.w);
}
__device__ __forceinline__ short8 comb(short4v a, short4v b){
  short8 r; r[0]=a[0]; r[1]=a[1]; r[2]=a[2]; r[3]=a[3];
  r[4]=b[0]; r[5]=b[1]; r[6]=b[2]; r[7]=b[3]; return r;
}

// ---------------- generic bt-GEMM (BK=64, two register sets) ----------------
// C[m][n] = sum_k A[m][k]*B[n][k], both row-major.
// TS: output tile. ABF/BBF: operand bf16 (1) or f32 fused-convert (0).
// NT=3: Markidis 3-term. EPI=1: +cvec[row]. OB=1: bf16 out.
template<int TS, int ABF, int BBF, int NT, int EPI, int OB>
__global__ __launch_bounds__(256, 2) void gemm_bt(
    const void* __restrict__ Av, const void* __restrict__ Bv,
    void* __restrict__ Cv, const float* __restrict__ cvec,
    int tn, int K, int lda, int ldb, int ldc,
    long sA, long sB, long sC, long scv)
{
  const int bz = blockIdx.y;
  const int mt = blockIdx.x / tn, nt = blockIdx.x % tn;
  const int m0 = mt * TS, n0 = nt * TS;

  constexpr int MI   = TS / 64;
  constexpr int ROWE = TS * 32;                      // shorts per 32-K plane
  constexpr int PL   = (NT == 3) ? 2 * ROWE : ROWE;  // shorts per sub per tensor
  constexpr int TBYT = 4 * PL;                       // bytes per tensor (2 subs)
  constexpr int SB   = (2 * TBYT > 16384) ? 2 * TBYT : 16384;
  constexpr int EL   = (TS == 128) ? 16 : 8;
  __shared__ __align__(16) char SMEM[SB];
  short* Ah  = (short*)SMEM;
  short* Bh2 = (short*)(SMEM + TBYT);
  float* EP  = (float*)SMEM;

  const int t = threadIdx.x;
  const int lane = t & 63, wid = t >> 6;
  const int rowS = (TS == 128) ? (t >> 1) : (t >> 2);
  const int kh   = (TS == 128) ? (t & 1)  : (t & 3);
  const int wr = wid >> 1, wc = wid & 1;
  const int fr = lane & 15, fg = lane >> 4;

  f32x4 acc[2*MI][2*MI];
  const f32x4 Z = {0.f, 0.f, 0.f, 0.f};
  #pragma unroll
  for (int i = 0; i < 2*MI; i++)
    #pragma unroll
    for (int j = 0; j < 2*MI; j++) acc[i][j] = Z;

  const int wbase = rowS * 32;
  const int sw = (rowS >> 1) & 3;
  const int i0 = wbase + ((((TS == 128) ? (kh << 1) : kh) ^ sw) << 3);
  const int i1 = (TS == 128) ? (wbase + ((((kh << 1) + 1) ^ sw) << 3)) : 0;

  const float*    Afp = (const float*)Av    + sA * bz + (long)(m0 + rowS) * lda + kh * EL;
  const ushort_t* Abp = (const ushort_t*)Av + sA * bz + (long)(m0 + rowS) * lda + kh * EL;
  const float*    Bfp = (const float*)Bv    + sB * bz + (long)(n0 + rowS) * ldb + kh * EL;
  const ushort_t* Bbp = (const ushort_t*)Bv + sB * bz + (long)(n0 + rowS) * ldb + kh * EL;

  struct Pf { float4 v[4]; };
  struct Ps { short8 v[2]; };
  Pf Af[2], Bf[2]; Ps As8[2], Bs8[2];

  auto loadA = [&](int s, int kk){
    if (ABF == 0){
      const float4* p = (const float4*)(Afp + kk);
      Af[s].v[0] = p[0]; Af[s].v[1] = p[1];
      if (TS == 128){ Af[s].v[2] = p[2]; Af[s].v[3] = p[3]; }
    } else {
      const short8* p = (const short8*)(Abp + kk);
      As8[s].v[0] = p[0]; if (TS == 128) As8[s].v[1] = p[1];
    }
  };
  auto loadB = [&](int s, int kk){
    if (BBF == 0){
      const float4* p = (const float4*)(Bfp + kk);
      Bf[s].v[0] = p[0]; Bf[s].v[1] = p[1];
      if (TS == 128){ Bf[s].v[2] = p[2]; Bf[s].v[3] = p[3]; }
    } else {
      const short8* p = (const short8*)(Bbp + kk);
      Bs8[s].v[0] = p[0]; if (TS == 128) Bs8[s].v[1] = p[1];
    }
  };

  auto stage = [&](int s){
    const int off = s * PL;
    if (ABF == 0){
      if (NT == 3){
        uint4 h0, l0; split8(Af[s].v[0], Af[s].v[1], h0, l0);
        *(uint4*)&Ah[off + i0] = h0; *(uint4*)&Ah[off + i0 + ROWE] = l0;
        if (TS == 128){
          uint4 h1, l1; split8(Af[s].v[2], Af[s].v[3], h1, l1);
          *(uint4*)&Ah[off + i1] = h1; *(uint4*)&Ah[off + i1 + ROWE] = l1;
        }
      } else {
        *(uint4*)&Ah[off + i0] = hi8(Af[s].v[0], Af[s].v[1]);
        if (TS == 128) *(uint4*)&Ah[off + i1] = hi8(Af[s].v[2], Af[s].v[3]);
      }
    } else {
      *(short8*)&Ah[off + i0] = As8[s].v[0];
      if (TS == 128) *(short8*)&Ah[off + i1] = As8[s].v[1];
    }
    if (BBF == 0){
      if (NT == 3){
        uint4 h0, l0; split8(Bf[s].v[0], Bf[s].v[1], h0, l0);
        *(uint4*)&Bh2[off + i0] = h0; *(uint4*)&Bh2[off + i0 + ROWE] = l0;
        if (TS == 128){
          uint4 h1, l1; split8(Bf[s].v[2], Bf[s].v[3], h1, l1);
          *(uint4*)&Bh2[off + i1] = h1; *(uint4*)&Bh2[off + i1 + ROWE] = l1;
        }
      } else {
        *(uint4*)&Bh2[off + i0] = hi8(Bf[s].v[0], Bf[s].v[1]);
        if (TS == 128) *(uint4*)&Bh2[off + i1] = hi8(Bf[s].v[2], Bf[s].v[3]);
      }
    } else {
      *(short8*)&Bh2[off + i0] = Bs8[s].v[0];
      if (TS == 128) *(short8*)&Bh2[off + i1] = Bs8[s].v[1];
    }
  };

  loadA(0, 0); loadB(0, 0); loadA(1, 32); loadB(1, 32);

  for (int k0 = 0; k0 < K; k0 += 64){
    barrier_lds();
    stage(0);
    { int kn = (k0 + 64 < K) ? (k0 + 64) : k0;       loadA(0, kn); loadB(0, kn); }
    stage(1);
    { int kn = (k0 + 64 < K) ? (k0 + 96) : (k0 + 32); loadA(1, kn); loadB(1, kn); }
    barrier_lds();

    #pragma unroll
    for (int s = 0; s < 2; s++){
      const int off = s * PL;
      short8 fa[2*MI], fb[2*MI], fal[2*MI], fbl[2*MI];
      #pragma unroll
      for (int mi = 0; mi < 2*MI; mi++){
        int r = wr * (32*MI) + mi * 16 + fr;
        int idx = off + r * 32 + ((fg ^ ((r >> 1) & 3)) << 3);
        fa[mi] = *(const short8*)&Ah[idx];
        if (NT == 3) fal[mi] = *(const short8*)&Ah[idx + ROWE];
      }
      #pragma unroll
      for (int ni = 0; ni < 2*MI; ni++){
        int r = wc * (32*MI) + ni * 16 + fr;
        int idx = off + r * 32 + ((fg ^ ((r >> 1) & 3)) << 3);
        fb[ni] = *(const short8*)&Bh2[idx];
        if (NT == 3) fbl[ni] = *(const short8*)&Bh2[idx + ROWE];
      }
      #pragma unroll
      for (int mi = 0; mi < 2*MI; mi++)
        #pragma unroll
        for (int ni = 0; ni < 2*MI; ni++){
          acc[mi][ni] = __builtin_amdgcn_mfma_f32_16x16x32_bf16(fa[mi], fb[ni], acc[mi][ni], 0, 0, 0);
          if (NT == 3){
            acc[mi][ni] = __builtin_amdgcn_mfma_f32_16x16x32_bf16(fal[mi], fb[ni],  acc[mi][ni], 0, 0, 0);
            acc[mi][ni] = __builtin_amdgcn_mfma_f32_16x16x32_bf16(fa[mi],  fbl[ni], acc[mi][ni], 0, 0, 0);
          }
        }
    }
  }

  // ---- coalesced epilogue via LDS restage ----
  float*    Cf = (float*)Cv    + sC * bz;
  ushort_t* Cb = (ushort_t*)Cv + sC * bz;
  if (TS == 128){
    #pragma unroll
    for (int p = 0; p < 4; p++){
      __syncthreads();
      if (wr == (p >> 1)){
        #pragma unroll
        for (int m2 = 0; m2 < 2; m2++){
          int mi = 2 * (p & 1) + m2;
          #pragma unroll
          for (int ni = 0; ni < 4; ni++)
            #pragma unroll
            for (int j = 0; j < 4; j++){
              int lr = m2 * 16 + fg * 4 + j;
              float o = acc[mi][ni][j];
              if (EPI == 1) o += cvec[scv * bz + m0 + p * 32 + lr];
              EP[lr * 128 + wc * 64 + ni * 16 + fr] = o;
            }
        }
      }
      __syncthreads();
      const int row = t >> 3, seg = t & 7;
      const float* src = EP + row * 128 + seg * 16;
      if (OB == 1){
        ushort_t* dst = Cb + (long)(m0 + p * 32 + row) * ldc + n0 + seg * 16;
        uint4 o0, o1;
        o0.x = cvt_pk(src[0], src[1]);  o0.y = cvt_pk(src[2], src[3]);
        o0.z = cvt_pk(src[4], src[5]);  o0.w = cvt_pk(src[6], src[7]);
        o1.x = cvt_pk(src[8], src[9]);  o1.y = cvt_pk(src[10], src[11]);
        o1.z = cvt_pk(src[12], src[13]); o1.w = cvt_pk(src[14], src[15]);
        *(uint4*)dst = o0; *(uint4*)(dst + 8) = o1;
      } else {
        float* dst = Cf + (long)(m0 + p * 32 + row) * ldc + n0 + seg * 16;
        #pragma unroll
        for (int c = 0; c < 4; c++)
          *(float4*)(dst + c * 4) = *(const float4*)(src + c * 4);
      }
    }
  } else {
    __syncthreads();
    #pragma unroll
    for (int mi = 0; mi < 2; mi++)
      #pragma unroll
      for (int ni = 0; ni < 2; ni++)
        #pragma unroll
        for (int j = 0; j < 4; j++){
          int lr = wr * 32 + mi * 16 + fg * 4 + j;
          float o = acc[mi][ni][j];
          if (EPI == 1) o += cvec[scv * bz + m0 + lr];
          EP[lr * 64 + wc * 32 + ni * 16 + fr] = o;
        }
    __syncthreads();
    const int row = t >> 2, seg = t & 3;
    const float* src = EP + row * 64 + seg * 16;
    if (OB == 1){
      ushort_t* dst = Cb + (long)(m0 + row) * ldc + n0 + seg * 16;
      uint4 o0, o1;
      o0.x = cvt_pk(src[0], src[1]);  o0.y = cvt_pk(src[2], src[3]);
      o0.z = cvt_pk(src[4], src[5]);  o0.w = cvt_pk(src[6], src[7]);
      o1.x = cvt_pk(src[8], src[9]);  o1.y = cvt_pk(src[10], src[11]);
      o1.z = cvt_pk(src[12], src[13]); o1.w = cvt_pk(src[14], src[15]);
      *(uint4*)dst = o0; *(uint4*)(dst + 8) = o1;
    } else {
      float* dst = Cf + (long)(m0 + row) * ldc + n0 + seg * 16;
      #pragma unroll
      for (int c = 0; c < 4; c++)
        *(float4*)(dst + c * 4) = *(const float4*)(src + c * 4);
    }
  }
}

// ---------------- GEMM1: Mt[b][kc][qc] = sum_s k[b][s][kc]*q[b][s][qc] ------
// 2-TERM split: k = hi+lo, q = hi only (absmax 0.039 < 0.0906 budget).
// NSP=8 (2 blocks/CU; NSP=4 = 1 block/CU loses barrier overlap, R10).
// launch_bounds (256,2): (256,4) caps VGPR at 64 -> spills (R5).
template<int NSP>
__global__ __launch_bounds__(256, 2) void gemm1_tn(
    const float* __restrict__ q, const float* __restrict__ k,
    float* __restrict__ mtp, float* __restrict__ sqp, float* __restrict__ skp)
{
  constexpr int CH = 8192 / NSP;
  constexpr int STEPS = CH / 64;
  const int b = blockIdx.z, sp = blockIdx.y;
  const int mt = blockIdx.x >> 2, nt = blockIdx.x & 3;
  const float* qb = q + (long)b * 8192 * 512;
  const float* kb = k + (long)b * 8192 * 512;

  __shared__ __align__(16) char SMEM[65536];
  unsigned char* As = (unsigned char*)SMEM;            // k: hi+lo, 16KB/sub
  unsigned char* Bs = (unsigned char*)(SMEM + 32768);  // q: hi only

  const int t = threadIdx.x;
  const int lam = t & 31, sg = t >> 5;
  const int lane = t & 63, wid = t >> 6;
  const int wr = wid >> 1, wc = wid & 1;
  const int fr = lane & 15, fg = lane >> 4;

  f32x4 acc[4][4];
  const f32x4 Z = {0.f, 0.f, 0.f, 0.f};
  #pragma unroll
  for (int i = 0; i < 4; i++)
    #pragma unroll
    for (int j = 0; j < 4; j++) acc[i][j] = Z;

  float sumk4[4] = {0.f, 0.f, 0.f, 0.f};
  float sumq4[4] = {0.f, 0.f, 0.f, 0.f};

  int wA[4];
  #pragma unroll
  for (int j = 0; j < 4; j++){
    int c = lam * 4 + j;
    int swc = ((c >> 2) ^ ((c & 3) << 1)) & 7;
    wA[j] = c * 128 + ((sg ^ swc) << 4);
  }

  const float* kbase = kb + (long)(sp * CH + sg * 4) * 512 + mt * 128 + lam * 4;
  const float* qbase = qb + (long)(sp * CH + sg * 4) * 512 + nt * 128 + lam * 4;

  struct Pf { float4 v[4]; };
  Pf Kf[2], Qf[2];

  auto ldK = [&](int s, int st){
    const float* p = kbase + (long)(st * 64 + s * 32) * 512;
    Kf[s].v[0] = *(const float4*)(p);
    Kf[s].v[1] = *(const float4*)(p + 512);
    Kf[s].v[2] = *(const float4*)(p + 1024);
    Kf[s].v[3] = *(const float4*)(p + 1536);
  };
  auto ldQ = [&](int s, int st){
    const float* p = qbase + (long)(st * 64 + s * 32) * 512;
    Qf[s].v[0] = *(const float4*)(p);
    Qf[s].v[1] = *(const float4*)(p + 512);
    Qf[s].v[2] = *(const float4*)(p + 1024);
    Qf[s].v[3] = *(const float4*)(p + 1536);
  };

  auto cvK = [&](int s){
    #pragma unroll
    for (int j = 0; j < 4; j++){
      float a0 = ((const float*)&Kf[s].v[0])[j], a1 = ((const float*)&Kf[s].v[1])[j];
      float a2 = ((const float*)&Kf[s].v[2])[j], a3 = ((const float*)&Kf[s].v[3])[j];
      sumk4[j] += (a0 + a1) + (a2 + a3);
      unsigned h0, h1, l0, l1;
      split4(a0, a1, a2, a3, h0, h1, l0, l1);
      uint4 w; w.x = h0; w.y = h1; w.z = l0; w.w = l1;
      *(uint4*)(As + s * 16384 + wA[j]) = w;
    }
  };
  auto cvQ = [&](int s){   // hi only
    #pragma unroll
    for (int j = 0; j < 4; j++){
      float a0 = ((const float*)&Qf[s].v[0])[j], a1 = ((const float*)&Qf[s].v[1])[j];
      float a2 = ((const float*)&Qf[s].v[2])[j], a3 = ((const float*)&Qf[s].v[3])[j];
      sumq4[j] += (a0 + a1) + (a2 + a3);
      uint2 w2; w2.x = cvt_pk(a0, a1); w2.y = cvt_pk(a2, a3);
      *(uint2*)(Bs + s * 16384 + wA[j]) = w2;
    }
  };

  ldK(0, 0); ldQ(0, 0); ldK(1, 0); ldQ(1, 0);

  for (int st = 0; st < STEPS; ++st){
    barrier_lds();
    cvK(0); cvQ(0);
    { int ns = (st < STEPS - 1) ? (st + 1) : st; ldK(0, ns); ldQ(0, ns); }
    cvK(1); cvQ(1);
    { int ns = (st < STEPS - 1) ? (st + 1) : st; ldK(1, ns); ldQ(1, ns); }
    barrier_lds();

    #pragma unroll
    for (int s = 0; s < 2; s++){
      const unsigned char* Ab = As + s * 16384;
      const unsigned char* Bb = Bs + s * 16384;
      short8 fa[4], fal[4], fb[4];
      #pragma unroll
      for (int mi = 0; mi < 4; mi++){
        int r = wr * 64 + mi * 16 + fr;
        int swc = ((r >> 2) ^ ((r & 3) << 1)) & 7;
        const unsigned char* bp = Ab + r * 128;
        int u0 = (((fg << 1) + 0) ^ swc) << 4;
        int u1 = (((fg << 1) + 1) ^ swc) << 4;
        fa[mi]  = comb(*(const short4v*)(bp + u0),     *(const short4v*)(bp + u1));
        fal[mi] = comb(*(const short4v*)(bp + u0 + 8), *(const short4v*)(bp + u1 + 8));
      }
      #pragma unroll
      for (int ni = 0; ni < 4; ni++){
        int r = wc * 64 + ni * 16 + fr;
        int swc = ((r >> 2) ^ ((r & 3) << 1)) & 7;
        const unsigned char* bp = Bb + r * 128;
        int u0 = (((fg << 1) + 0) ^ swc) << 4;
        int u1 = (((fg << 1) + 1) ^ swc) << 4;
        fb[ni]  = comb(*(const short4v*)(bp + u0), *(const short4v*)(bp + u1));
      }
      #pragma unroll
      for (int mi = 0; mi < 4; mi++)
        #pragma unroll
        for (int ni = 0; ni < 4; ni++){
          acc[mi][ni] = __builtin_amdgcn_mfma_f32_16x16x32_bf16(fa[mi],  fb[ni], acc[mi][ni], 0, 0, 0);
          acc[mi][ni] = __builtin_amdgcn_mfma_f32_16x16x32_bf16(fal[mi], fb[ni], acc[mi][ni], 0, 0, 0);
        }
    }
  }

  float* Cp = mtp + ((long)sp * 4 + b) * (512 * 512);
  #pragma unroll
  for (int mi = 0; mi < 4; mi++)
    #pragma unroll
    for (int ni = 0; ni < 4; ni++){
      int gr0 = mt * 128 + wr * 64 + mi * 16 + fg * 4;
      int gc  = nt * 128 + wc * 64 + ni * 16 + fr;
      #pragma unroll
      for (int j = 0; j < 4; j++)
        Cp[(long)(gr0 + j) * 512 + gc] = acc[mi][ni][j];
    }

  __syncthreads();
  float* red = (float*)SMEM;
  if (mt == 0){
    #pragma unroll
    for (int j = 0; j < 4; j++) red[sg * 128 + lam * 4 + j] = sumq4[j];
    __syncthreads();
    if (t < 128){
      float s2 = 0.f;
      #pragma unroll
      for (int gg = 0; gg < 8; gg++) s2 += red[gg * 128 + t];
      sqp[((long)b * NSP + sp) * 512 + nt * 128 + t] = s2;
    }
    __syncthreads();
  }
  if (nt == 0){
    #pragma unroll
    for (int j = 0; j < 4; j++) red[sg * 128 + lam * 4 + j] = sumk4[j];
    __syncthreads();
    if (t < 128){
      float s2 = 0.f;
      #pragma unroll
      for (int gg = 0; gg < 8; gg++) s2 += red[gg * 128 + t];
      skp[((long)b * NSP + sp) * 512 + mt * 128 + t] = s2;
    }
  }
}

// ---------------- midprep: reduceM + transpose512 + smallprep fused ---------
template<int NS>
__global__ __launch_bounds__(256) void midprep(
    float* __restrict__ p,
    const float* __restrict__ Wv, float* __restrict__ wvT,
    const float* __restrict__ sqp, const float* __restrict__ skp,
    const float* __restrict__ Wq, const float* __restrict__ Wk,
    float* __restrict__ wqsq, float* __restrict__ wksk)
{
  __shared__ float shm[33 * 32];
  const int bid = blockIdx.x;
  const int t = threadIdx.x;
  if (bid < 1024){
    const int b = bid >> 8;
    const long i = (long)(bid & 255) * 1024 + t * 4;
    float4 s = {0.f, 0.f, 0.f, 0.f};
    #pragma unroll
    for (int j = 0; j < NS; j++){
      float4 v = *(const float4*)(p + ((long)j * 4 + b) * 262144 + i);
      s.x += v.x; s.y += v.y; s.z += v.z; s.w += v.w;
    }
    *(float4*)(p + (long)b * 262144 + i) = s;
  } else if (bid < 1280){
    const int bb = bid - 1024;
    const int bx = bb & 15, by = bb >> 4;
    const int tx = t & 31, ty = t >> 5;
    float (*tile)[33] = (float(*)[33])shm;
    #pragma unroll
    for (int r = 0; r < 4; r++)
      tile[ty + 8*r][tx] = Wv[(long)(by*32 + ty + 8*r) * 512 + bx*32 + tx];
    __syncthreads();
    #pragma unroll
    for (int r = 0; r < 4; r++)
      wvT[(long)(bx*32 + ty + 8*r) * 512 + by*32 + tx] = tile[tx][ty + 8*r];
  } else {
    const int bb = bid - 1280;
    const int tau = bb >> 4;
    const int b = (bb >> 2) & 3, ab = bb & 3;
    const float* P = tau ? skp : sqp;
    const float* W = tau ? Wk : Wq;
    float* O = tau ? wksk : wqsq;
    float* sv = shm;
    for (int i = t; i < 512; i += 256){
      float s = 0.f;
      #pragma unroll
      for (int g = 0; g < NS; g++) s += P[((long)b * NS + g) * 512 + i];
      sv[i] = s;
    }
    __syncthreads();
    const int a = ab * 128 + (t >> 1), half = t & 1;
    const float* Wr = W + (long)a * 512 + half * 256;
    const float* sp2 = sv + half * 256;
    float d = 0.f;
    #pragma unroll 8
    for (int j = 0; j < 256; j++) d += Wr[j] * sp2[j];
    d += __shfl_xor(d, 1);
    if (!half) O[(long)b * 512 + a] = d;
  }
}

__global__ __launch_bounds__(256) void softmax_k(
    const float* __restrict__ num, float* __restrict__ attn, float* __restrict__ cv,
    const float* __restrict__ wqsq, const float* __restrict__ wksk,
    const float* __restrict__ bq, const float* __restrict__ bk,
    const float* __restrict__ bv, const int* __restrict__ gt)
{
  const int a = blockIdx.x, b = blockIdx.y;
  const int t = threadIdx.x;
  const int lane = t & 63, wid = t >> 6;
  __shared__ unsigned char gf[512];
  __shared__ float red[4];
  gf[t] = 0; gf[t + 256] = 0;
  __syncthreads();
  if (t < 64) gf[gt[t]] = 1;
  __syncthreads();

  const float* row = num + ((long)b * 512 + a) * 512;
  const float bqa = bq[a], wqa = wqsq[b * 512 + a];
  const int ga = gf[a];
  const int c0 = t, c1 = t + 256;
  float l0 = (row[c0] + wqa * bk[c0] + bqa * wksk[b*512 + c0] + 8192.0f * bqa * bk[c0]) * 0.04419417382415922f;
  float l1 = (row[c1] + wqa * bk[c1] + bqa * wksk[b*512 + c1] + 8192.0f * bqa * bk[c1]) * 0.04419417382415922f;
  if (a < c0 && !ga && !gf[c0]) l0 = -1e30f;
  if (a < c1 && !ga && !gf[c1]) l1 = -1e30f;

  float m = fmaxf(l0, l1);
  #pragma unroll
  for (int o = 32; o; o >>= 1) m = fmaxf(m, __shfl_xor(m, o));
  if (lane == 0) red[wid] = m;
  __syncthreads();
  m = fmaxf(fmaxf(red[0], red[1]), fmaxf(red[2], red[3]));
  __syncthreads();

  float e0 = __expf(l0 - m), e1 = __expf(l1 - m);
  float s = e0 + e1;
  #pragma unroll
  for (int o = 32; o; o >>= 1) s += __shfl_xor(s, o);
  if (lane == 0) red[wid] = s;
  __syncthreads();
  s = red[0] + red[1] + red[2] + red[3];
  __syncthreads();
  const float inv = 1.0f / s;
  const float a0 = e0 * inv, a1 = e1 * inv;
  float* arow = attn + ((long)b * 512 + a) * 512;
  arow[c0] = a0; arow[c1] = a1;

  float cp = a0 * bv[c0] + a1 * bv[c1];
  #pragma unroll
  for (int o = 32; o; o >>= 1) cp += __shfl_xor(cp, o);
  if (lane == 0) red[wid] = cp;
  __syncthreads();
  if (t == 0) cv[(long)b * 512 + a] = red[0] + red[1] + red[2] + red[3];
}

// ---------------- launch -----------------------------------------------------
extern "C" void kernel_launch(void* const* d_in, const int* in_sizes, int n_in,
                              void* d_out, int out_size, void* d_ws, size_t ws_size,
                              hipStream_t stream) {
  const float* q  = (const float*)d_in[0];
  const float* k  = (const float*)d_in[1];
  const float* v  = (const float*)d_in[2];
  const float* Wq = (const float*)d_in[3];
  const float* bq = (const float*)d_in[4];
  const float* Wk = (const float*)d_in[5];
  const float* bk = (const float*)d_in[6];
  const float* Wv = (const float*)d_in[7];
  const float* bv = (const float*)d_in[8];
  const int*   gt = (const int*)d_in[9];
  float* out = (float*)d_out;

  float* w = (float*)d_ws;
  float* MT   = w;                          // slice 0 after in-place reduce
  float* T1   = w + 1048576;
  float* NUM  = w + 2097152;
  float* ATT  = w + 3145728;
  float* A2H  = w + 4194304;                // 524288 f32 = 1M ushorts
  float* WVT  = A2H + 524288;               // 262144
  float* SM   = w + 8L * 1048576;           // smalls past slice region
  float* SQP  = SM;
  float* SKP  = SQP + 32768;
  float* WQS  = SKP + 32768;
  float* WKS  = WQS + 2048;
  float* CV   = WKS + 2048;
  ushort_t* a2h = (ushort_t*)A2H;

  gemm1_tn<8><<<dim3(16, 8, 4), 256, 0, stream>>>(q, k, w, SQP, SKP);
  midprep<8><<<1312, 256, 0, stream>>>(w, Wv, WVT, SQP, SKP, Wq, Wk, WQS, WKS);
  // T1[a][j] = sum_i Wq[a][i] * MT[j][i]
  gemm_bt<64,0,0,3,0,0><<<dim3(64, 4), 256, 0, stream>>>(Wq, MT, T1, nullptr,
      8, 512, 512, 512, 512, 0L, 262144L, 262144L, 0L);
  // NUM[a][c] = sum_j T1[a][j] * Wk[c][j]
  gemm_bt<64,0,0,3,0,0><<<dim3(64, 4), 256, 0, stream>>>(T1, Wk, NUM, nullptr,
      8, 512, 512, 512, 512, 262144L, 0L, 262144L, 0L);
  softmax_k<<<dim3(512, 4), 256, 0, stream>>>(NUM, ATT, CV, WQS, WKS, bq, bk, bv, gt);
  // A2[a][i] = sum_c attn[a][c] * WvT[i][c] -> bf16
  gemm_bt<64,0,0,1,0,1><<<dim3(64, 4), 256, 0, stream>>>(ATT, WVT, a2h, nullptr,
      8, 512, 512, 512, 512, 262144L, 0L, 262144L, 0L);
  // out[a][s] = sum_i A2[a][i] * v[s][i] + cv[a]   (A bf16)
  gemm_bt<128,1,0,1,1,0><<<dim3(256, 4), 256, 0, stream>>>(a2h, v, out, CV,
      64, 512, 512, 512, 8192, 262144L, 4194304L, 4194304L, 512L);
}

// Round 15
// 187.832 us; speedup vs baseline: 1.0956x; 1.0026x over previous
//
#include <hip/hip_runtime.h>
#include <stdint.h>

typedef short short8 __attribute__((ext_vector_type(8)));
typedef short short4v __attribute__((ext_vector_type(4)));
typedef float f32x4 __attribute__((ext_vector_type(4)));
typedef unsigned short ushort_t;

// barrier with LDS-only drain (global->register prefetches stay in flight)
__device__ __forceinline__ void barrier_lds(){
  asm volatile("s_waitcnt lgkmcnt(0)\n\ts_barrier" ::: "memory");
}

__device__ __forceinline__ unsigned short bf16_rne(float x){
  unsigned int u = __float_as_uint(x);
  return (unsigned short)((u + 0x7FFFu + ((u >> 16) & 1u)) >> 16);
}
__device__ __forceinline__ unsigned cvt_pk(float a, float b){
  unsigned r;
  asm("v_cvt_pk_bf16_f32 %0, %1, %2" : "=v"(r) : "v"(a), "v"(b));
  return r;
}
__device__ __forceinline__ void split4(float a0, float a1, float a2, float a3,
                                       unsigned &h0, unsigned &h1,
                                       unsigned &l0, unsigned &l1){
  h0 = cvt_pk(a0, a1); h1 = cvt_pk(a2, a3);
  float f0 = __uint_as_float(h0 << 16), f1 = __uint_as_float(h0 & 0xFFFF0000u);
  float f2 = __uint_as_float(h1 << 16), f3 = __uint_as_float(h1 & 0xFFFF0000u);
  l0 = cvt_pk(a0 - f0, a1 - f1); l1 = cvt_pk(a2 - f2, a3 - f3);
}
__device__ __forceinline__ uint4 hi8(float4 x, float4 y){
  uint4 h; h.x = cvt_pk(x.x, x.y); h.y = cvt_pk(x.z, x.w);
  h.z = cvt_pk(y.x, y.y); h.w = cvt_pk(y.z, y.w); return h;
}
__device__ __forceinline__ void split8(float4 x, float4 y, uint4 &h, uint4 &l){
  split4(x.x, x.y, x.z, x.w, h.x, h.y, l.x, l.y);
  split4(y.x, y.y, y.z, y.w, h.z, h.w, l.z, l.w);
}
__device__ __forceinline__ short8 comb(short4v a, short4v b){
  short8 r; r[0]=a[0]; r[1]=a[1]; r[2]=a[2]; r[3]=a[3];
  r[4]=b[0]; r[5]=b[1]; r[6]=b[2]; r[7]=b[3]; return r;
}

// ---------------- generic bt-GEMM (BK=64, two register sets) ----------------
// C[m][n] = sum_k A[m][k]*B[n][k], both row-major.
// TS: output tile. ABF/BBF: operand bf16 (1) or f32 fused-convert (0).
// NT=3: Markidis 3-term. EPI=1: +cvec[row]. OB=1: bf16 out.
template<int TS, int ABF, int BBF, int NT, int EPI, int OB>
__global__ __launch_bounds__(256, 2) void gemm_bt(
    const void* __restrict__ Av, const void* __restrict__ Bv,
    void* __restrict__ Cv, const float* __restrict__ cvec,
    int tn, int K, int lda, int ldb, int ldc,
    long sA, long sB, long sC, long scv)
{
  const int bz = blockIdx.y;
  const int mt = blockIdx.x / tn, nt = blockIdx.x % tn;
  const int m0 = mt * TS, n0 = nt * TS;

  constexpr int MI   = TS / 64;
  constexpr int ROWE = TS * 32;                      // shorts per 32-K plane
  constexpr int PL   = (NT == 3) ? 2 * ROWE : ROWE;  // shorts per sub per tensor
  constexpr int TBYT = 4 * PL;                       // bytes per tensor (2 subs)
  constexpr int SB   = (2 * TBYT > 16384) ? 2 * TBYT : 16384;
  constexpr int EL   = (TS == 128) ? 16 : 8;
  __shared__ __align__(16) char SMEM[SB];
  short* Ah  = (short*)SMEM;
  short* Bh2 = (short*)(SMEM + TBYT);
  float* EP  = (float*)SMEM;

  const int t = threadIdx.x;
  const int lane = t & 63, wid = t >> 6;
  const int rowS = (TS == 128) ? (t >> 1) : (t >> 2);
  const int kh   = (TS == 128) ? (t & 1)  : (t & 3);
  const int wr = wid >> 1, wc = wid & 1;
  const int fr = lane & 15, fg = lane >> 4;

  f32x4 acc[2*MI][2*MI];
  const f32x4 Z = {0.f, 0.f, 0.f, 0.f};
  #pragma unroll
  for (int i = 0; i < 2*MI; i++)
    #pragma unroll
    for (int j = 0; j < 2*MI; j++) acc[i][j] = Z;

  const int wbase = rowS * 32;
  const int sw = (rowS >> 1) & 3;
  const int i0 = wbase + ((((TS == 128) ? (kh << 1) : kh) ^ sw) << 3);
  const int i1 = (TS == 128) ? (wbase + ((((kh << 1) + 1) ^ sw) << 3)) : 0;

  const float*    Afp = (const float*)Av    + sA * bz + (long)(m0 + rowS) * lda + kh * EL;
  const ushort_t* Abp = (const ushort_t*)Av + sA * bz + (long)(m0 + rowS) * lda + kh * EL;
  const float*    Bfp = (const float*)Bv    + sB * bz + (long)(n0 + rowS) * ldb + kh * EL;
  const ushort_t* Bbp = (const ushort_t*)Bv + sB * bz + (long)(n0 + rowS) * ldb + kh * EL;

  struct Pf { float4 v[4]; };
  struct Ps { short8 v[2]; };
  Pf Af[2], Bf[2]; Ps As8[2], Bs8[2];

  auto loadA = [&](int s, int kk){
    if (ABF == 0){
      const float4* p = (const float4*)(Afp + kk);
      Af[s].v[0] = p[0]; Af[s].v[1] = p[1];
      if (TS == 128){ Af[s].v[2] = p[2]; Af[s].v[3] = p[3]; }
    } else {
      const short8* p = (const short8*)(Abp + kk);
      As8[s].v[0] = p[0]; if (TS == 128) As8[s].v[1] = p[1];
    }
  };
  auto loadB = [&](int s, int kk){
    if (BBF == 0){
      const float4* p = (const float4*)(Bfp + kk);
      Bf[s].v[0] = p[0]; Bf[s].v[1] = p[1];
      if (TS == 128){ Bf[s].v[2] = p[2]; Bf[s].v[3] = p[3]; }
    } else {
      const short8* p = (const short8*)(Bbp + kk);
      Bs8[s].v[0] = p[0]; if (TS == 128) Bs8[s].v[1] = p[1];
    }
  };

  auto stage = [&](int s){
    const int off = s * PL;
    if (ABF == 0){
      if (NT == 3){
        uint4 h0, l0; split8(Af[s].v[0], Af[s].v[1], h0, l0);
        *(uint4*)&Ah[off + i0] = h0; *(uint4*)&Ah[off + i0 + ROWE] = l0;
        if (TS == 128){
          uint4 h1, l1; split8(Af[s].v[2], Af[s].v[3], h1, l1);
          *(uint4*)&Ah[off + i1] = h1; *(uint4*)&Ah[off + i1 + ROWE] = l1;
        }
      } else {
        *(uint4*)&Ah[off + i0] = hi8(Af[s].v[0], Af[s].v[1]);
        if (TS == 128) *(uint4*)&Ah[off + i1] = hi8(Af[s].v[2], Af[s].v[3]);
      }
    } else {
      *(short8*)&Ah[off + i0] = As8[s].v[0];
      if (TS == 128) *(short8*)&Ah[off + i1] = As8[s].v[1];
    }
    if (BBF == 0){
      if (NT == 3){
        uint4 h0, l0; split8(Bf[s].v[0], Bf[s].v[1], h0, l0);
        *(uint4*)&Bh2[off + i0] = h0; *(uint4*)&Bh2[off + i0 + ROWE] = l0;
        if (TS == 128){
          uint4 h1, l1; split8(Bf[s].v[2], Bf[s].v[3], h1, l1);
          *(uint4*)&Bh2[off + i1] = h1; *(uint4*)&Bh2[off + i1 + ROWE] = l1;
        }
      } else {
        *(uint4*)&Bh2[off + i0] = hi8(Bf[s].v[0], Bf[s].v[1]);
        if (TS == 128) *(uint4*)&Bh2[off + i1] = hi8(Bf[s].v[2], Bf[s].v[3]);
      }
    } else {
      *(short8*)&Bh2[off + i0] = Bs8[s].v[0];
      if (TS == 128) *(short8*)&Bh2[off + i1] = Bs8[s].v[1];
    }
  };

  loadA(0, 0); loadB(0, 0); loadA(1, 32); loadB(1, 32);

  for (int k0 = 0; k0 < K; k0 += 64){
    barrier_lds();
    stage(0);
    { int kn = (k0 + 64 < K) ? (k0 + 64) : k0;       loadA(0, kn); loadB(0, kn); }
    stage(1);
    { int kn = (k0 + 64 < K) ? (k0 + 96) : (k0 + 32); loadA(1, kn); loadB(1, kn); }
    barrier_lds();

    #pragma unroll
    for (int s = 0; s < 2; s++){
      const int off = s * PL;
      short8 fa[2*MI], fb[2*MI], fal[2*MI], fbl[2*MI];
      #pragma unroll
      for (int mi = 0; mi < 2*MI; mi++){
        int r = wr * (32*MI) + mi * 16 + fr;
        int idx = off + r * 32 + ((fg ^ ((r >> 1) & 3)) << 3);
        fa[mi] = *(const short8*)&Ah[idx];
        if (NT == 3) fal[mi] = *(const short8*)&Ah[idx + ROWE];
      }
      #pragma unroll
      for (int ni = 0; ni < 2*MI; ni++){
        int r = wc * (32*MI) + ni * 16 + fr;
        int idx = off + r * 32 + ((fg ^ ((r >> 1) & 3)) << 3);
        fb[ni] = *(const short8*)&Bh2[idx];
        if (NT == 3) fbl[ni] = *(const short8*)&Bh2[idx + ROWE];
      }
      #pragma unroll
      for (int mi = 0; mi < 2*MI; mi++)
        #pragma unroll
        for (int ni = 0; ni < 2*MI; ni++){
          acc[mi][ni] = __builtin_amdgcn_mfma_f32_16x16x32_bf16(fa[mi], fb[ni], acc[mi][ni], 0, 0, 0);
          if (NT == 3){
            acc[mi][ni] = __builtin_amdgcn_mfma_f32_16x16x32_bf16(fal[mi], fb[ni],  acc[mi][ni], 0, 0, 0);
            acc[mi][ni] = __builtin_amdgcn_mfma_f32_16x16x32_bf16(fa[mi],  fbl[ni], acc[mi][ni], 0, 0, 0);
          }
        }
    }
  }

  // ---- coalesced epilogue via LDS restage ----
  float*    Cf = (float*)Cv    + sC * bz;
  ushort_t* Cb = (ushort_t*)Cv + sC * bz;
  if (TS == 128){
    #pragma unroll
    for (int p = 0; p < 4; p++){
      __syncthreads();
      if (wr == (p >> 1)){
        #pragma unroll
        for (int m2 = 0; m2 < 2; m2++){
          int mi = 2 * (p & 1) + m2;
          #pragma unroll
          for (int ni = 0; ni < 4; ni++)
            #pragma unroll
            for (int j = 0; j < 4; j++){
              int lr = m2 * 16 + fg * 4 + j;
              float o = acc[mi][ni][j];
              if (EPI == 1) o += cvec[scv * bz + m0 + p * 32 + lr];
              EP[lr * 128 + wc * 64 + ni * 16 + fr] = o;
            }
        }
      }
      __syncthreads();
      const int row = t >> 3, seg = t & 7;
      const float* src = EP + row * 128 + seg * 16;
      if (OB == 1){
        ushort_t* dst = Cb + (long)(m0 + p * 32 + row) * ldc + n0 + seg * 16;
        uint4 o0, o1;
        o0.x = cvt_pk(src[0], src[1]);  o0.y = cvt_pk(src[2], src[3]);
        o0.z = cvt_pk(src[4], src[5]);  o0.w = cvt_pk(src[6], src[7]);
        o1.x = cvt_pk(src[8], src[9]);  o1.y = cvt_pk(src[10], src[11]);
        o1.z = cvt_pk(src[12], src[13]); o1.w = cvt_pk(src[14], src[15]);
        *(uint4*)dst = o0; *(uint4*)(dst + 8) = o1;
      } else {
        float* dst = Cf + (long)(m0 + p * 32 + row) * ldc + n0 + seg * 16;
        #pragma unroll
        for (int c = 0; c < 4; c++)
          *(float4*)(dst + c * 4) = *(const float4*)(src + c * 4);
      }
    }
  } else {
    __syncthreads();
    #pragma unroll
    for (int mi = 0; mi < 2; mi++)
      #pragma unroll
      for (int ni = 0; ni < 2; ni++)
        #pragma unroll
        for (int j = 0; j < 4; j++){
          int lr = wr * 32 + mi * 16 + fg * 4 + j;
          float o = acc[mi][ni][j];
          if (EPI == 1) o += cvec[scv * bz + m0 + lr];
          EP[lr * 64 + wc * 32 + ni * 16 + fr] = o;
        }
    __syncthreads();
    const int row = t >> 2, seg = t & 3;
    const float* src = EP + row * 64 + seg * 16;
    if (OB == 1){
      ushort_t* dst = Cb + (long)(m0 + row) * ldc + n0 + seg * 16;
      uint4 o0, o1;
      o0.x = cvt_pk(src[0], src[1]);  o0.y = cvt_pk(src[2], src[3]);
      o0.z = cvt_pk(src[4], src[5]);  o0.w = cvt_pk(src[6], src[7]);
      o1.x = cvt_pk(src[8], src[9]);  o1.y = cvt_pk(src[10], src[11]);
      o1.z = cvt_pk(src[12], src[13]); o1.w = cvt_pk(src[14], src[15]);
      *(uint4*)dst = o0; *(uint4*)(dst + 8) = o1;
    } else {
      float* dst = Cf + (long)(m0 + row) * ldc + n0 + seg * 16;
      #pragma unroll
      for (int c = 0; c < 4; c++)
        *(float4*)(dst + c * 4) = *(const float4*)(src + c * 4);
    }
  }
}

// ---------------- GEMM1: Mt[b][kc][qc] = sum_s k[b][s][kc]*q[b][s][qc] ------
// 2-TERM split: k = hi+lo, q = hi only (absmax 0.039 < 0.0906 budget).
// NSP=8 (2 blocks/CU). 16B-slot q layout: the packed 8B-slot variant (R14)
// FAILED correctness (absmax 0.31) for undiagnosed reasons -- do not retry
// without on-device layout verification.
// launch_bounds (256,2): (256,4) caps VGPR at 64 -> spills (R5).
template<int NSP>
__global__ __launch_bounds__(256, 2) void gemm1_tn(
    const float* __restrict__ q, const float* __restrict__ k,
    float* __restrict__ mtp, float* __restrict__ sqp, float* __restrict__ skp)
{
  constexpr int CH = 8192 / NSP;
  constexpr int STEPS = CH / 64;
  const int b = blockIdx.z, sp = blockIdx.y;
  const int mt = blockIdx.x >> 2, nt = blockIdx.x & 3;
  const float* qb = q + (long)b * 8192 * 512;
  const float* kb = k + (long)b * 8192 * 512;

  __shared__ __align__(16) char SMEM[65536];
  unsigned char* As = (unsigned char*)SMEM;            // k: hi+lo, 16KB/sub
  unsigned char* Bs = (unsigned char*)(SMEM + 32768);  // q: hi only

  const int t = threadIdx.x;
  const int lam = t & 31, sg = t >> 5;
  const int lane = t & 63, wid = t >> 6;
  const int wr = wid >> 1, wc = wid & 1;
  const int fr = lane & 15, fg = lane >> 4;

  f32x4 acc[4][4];
  const f32x4 Z = {0.f, 0.f, 0.f, 0.f};
  #pragma unroll
  for (int i = 0; i < 4; i++)
    #pragma unroll
    for (int j = 0; j < 4; j++) acc[i][j] = Z;

  float sumk4[4] = {0.f, 0.f, 0.f, 0.f};
  float sumq4[4] = {0.f, 0.f, 0.f, 0.f};

  int wA[4];
  #pragma unroll
  for (int j = 0; j < 4; j++){
    int c = lam * 4 + j;
    int swc = ((c >> 2) ^ ((c & 3) << 1)) & 7;
    wA[j] = c * 128 + ((sg ^ swc) << 4);
  }

  const float* kbase = kb + (long)(sp * CH + sg * 4) * 512 + mt * 128 + lam * 4;
  const float* qbase = qb + (long)(sp * CH + sg * 4) * 512 + nt * 128 + lam * 4;

  struct Pf { float4 v[4]; };
  Pf Kf[2], Qf[2];

  auto ldK = [&](int s, int st){
    const float* p = kbase + (long)(st * 64 + s * 32) * 512;
    Kf[s].v[0] = *(const float4*)(p);
    Kf[s].v[1] = *(const float4*)(p + 512);
    Kf[s].v[2] = *(const float4*)(p + 1024);
    Kf[s].v[3] = *(const float4*)(p + 1536);
  };
  auto ldQ = [&](int s, int st){
    const float* p = qbase + (long)(st * 64 + s * 32) * 512;
    Qf[s].v[0] = *(const float4*)(p);
    Qf[s].v[1] = *(const float4*)(p + 512);
    Qf[s].v[2] = *(const float4*)(p + 1024);
    Qf[s].v[3] = *(const float4*)(p + 1536);
  };

  auto cvK = [&](int s){
    #pragma unroll
    for (int j = 0; j < 4; j++){
      float a0 = ((const float*)&Kf[s].v[0])[j], a1 = ((const float*)&Kf[s].v[1])[j];
      float a2 = ((const float*)&Kf[s].v[2])[j], a3 = ((const float*)&Kf[s].v[3])[j];
      sumk4[j] += (a0 + a1) + (a2 + a3);
      unsigned h0, h1, l0, l1;
      split4(a0, a1, a2, a3, h0, h1, l0, l1);
      uint4 w; w.x = h0; w.y = h1; w.z = l0; w.w = l1;
      *(uint4*)(As + s * 16384 + wA[j]) = w;
    }
  };
  auto cvQ = [&](int s){   // hi only
    #pragma unroll
    for (int j = 0; j < 4; j++){
      float a0 = ((const float*)&Qf[s].v[0])[j], a1 = ((const float*)&Qf[s].v[1])[j];
      float a2 = ((const float*)&Qf[s].v[2])[j], a3 = ((const float*)&Qf[s].v[3])[j];
      sumq4[j] += (a0 + a1) + (a2 + a3);
      uint2 w2; w2.x = cvt_pk(a0, a1); w2.y = cvt_pk(a2, a3);
      *(uint2*)(Bs + s * 16384 + wA[j]) = w2;
    }
  };

  ldK(0, 0); ldQ(0, 0); ldK(1, 0); ldQ(1, 0);

  for (int st = 0; st < STEPS; ++st){
    barrier_lds();
    cvK(0); cvQ(0);
    { int ns = (st < STEPS - 1) ? (st + 1) : st; ldK(0, ns); ldQ(0, ns); }
    cvK(1); cvQ(1);
    { int ns = (st < STEPS - 1) ? (st + 1) : st; ldK(1, ns); ldQ(1, ns); }
    barrier_lds();

    #pragma unroll
    for (int s = 0; s < 2; s++){
      const unsigned char* Ab = As + s * 16384;
      const unsigned char* Bb = Bs + s * 16384;
      short8 fa[4], fal[4], fb[4];
      #pragma unroll
      for (int mi = 0; mi < 4; mi++){
        int r = wr * 64 + mi * 16 + fr;
        int swc = ((r >> 2) ^ ((r & 3) << 1)) & 7;
        const unsigned char* bp = Ab + r * 128;
        int u0 = (((fg << 1) + 0) ^ swc) << 4;
        int u1 = (((fg << 1) + 1) ^ swc) << 4;
        fa[mi]  = comb(*(const short4v*)(bp + u0),     *(const short4v*)(bp + u1));
        fal[mi] = comb(*(const short4v*)(bp + u0 + 8), *(const short4v*)(bp + u1 + 8));
      }
      #pragma unroll
      for (int ni = 0; ni < 4; ni++){
        int r = wc * 64 + ni * 16 + fr;
        int swc = ((r >> 2) ^ ((r & 3) << 1)) & 7;
        const unsigned char* bp = Bb + r * 128;
        int u0 = (((fg << 1) + 0) ^ swc) << 4;
        int u1 = (((fg << 1) + 1) ^ swc) << 4;
        fb[ni]  = comb(*(const short4v*)(bp + u0), *(const short4v*)(bp + u1));
      }
      #pragma unroll
      for (int mi = 0; mi < 4; mi++)
        #pragma unroll
        for (int ni = 0; ni < 4; ni++){
          acc[mi][ni] = __builtin_amdgcn_mfma_f32_16x16x32_bf16(fa[mi],  fb[ni], acc[mi][ni], 0, 0, 0);
          acc[mi][ni] = __builtin_amdgcn_mfma_f32_16x16x32_bf16(fal[mi], fb[ni], acc[mi][ni], 0, 0, 0);
        }
    }
  }

  float* Cp = mtp + ((long)sp * 4 + b) * (512 * 512);
  #pragma unroll
  for (int mi = 0; mi < 4; mi++)
    #pragma unroll
    for (int ni = 0; ni < 4; ni++){
      int gr0 = mt * 128 + wr * 64 + mi * 16 + fg * 4;
      int gc  = nt * 128 + wc * 64 + ni * 16 + fr;
      #pragma unroll
      for (int j = 0; j < 4; j++)
        Cp[(long)(gr0 + j) * 512 + gc] = acc[mi][ni][j];
    }

  __syncthreads();
  float* red = (float*)SMEM;
  if (mt == 0){
    #pragma unroll
    for (int j = 0; j < 4; j++) red[sg * 128 + lam * 4 + j] = sumq4[j];
    __syncthreads();
    if (t < 128){
      float s2 = 0.f;
      #pragma unroll
      for (int gg = 0; gg < 8; gg++) s2 += red[gg * 128 + t];
      sqp[((long)b * NSP + sp) * 512 + nt * 128 + t] = s2;
    }
    __syncthreads();
  }
  if (nt == 0){
    #pragma unroll
    for (int j = 0; j < 4; j++) red[sg * 128 + lam * 4 + j] = sumk4[j];
    __syncthreads();
    if (t < 128){
      float s2 = 0.f;
      #pragma unroll
      for (int gg = 0; gg < 8; gg++) s2 += red[gg * 128 + t];
      skp[((long)b * NSP + sp) * 512 + mt * 128 + t] = s2;
    }
  }
}

// ---------------- midprep: reduceM + transpose512 + smallprep fused ---------
template<int NS>
__global__ __launch_bounds__(256) void midprep(
    float* __restrict__ p,
    const float* __restrict__ Wv, float* __restrict__ wvT,
    const float* __restrict__ sqp, const float* __restrict__ skp,
    const float* __restrict__ Wq, const float* __restrict__ Wk,
    float* __restrict__ wqsq, float* __restrict__ wksk)
{
  __shared__ float shm[33 * 32];
  const int bid = blockIdx.x;
  const int t = threadIdx.x;
  if (bid < 1024){
    const int b = bid >> 8;
    const long i = (long)(bid & 255) * 1024 + t * 4;
    float4 s = {0.f, 0.f, 0.f, 0.f};
    #pragma unroll
    for (int j = 0; j < NS; j++){
      float4 v = *(const float4*)(p + ((long)j * 4 + b) * 262144 + i);
      s.x += v.x; s.y += v.y; s.z += v.z; s.w += v.w;
    }
    *(float4*)(p + (long)b * 262144 + i) = s;
  } else if (bid < 1280){
    const int bb = bid - 1024;
    const int bx = bb & 15, by = bb >> 4;
    const int tx = t & 31, ty = t >> 5;
    float (*tile)[33] = (float(*)[33])shm;
    #pragma unroll
    for (int r = 0; r < 4; r++)
      tile[ty + 8*r][tx] = Wv[(long)(by*32 + ty + 8*r) * 512 + bx*32 + tx];
    __syncthreads();
    #pragma unroll
    for (int r = 0; r < 4; r++)
      wvT[(long)(bx*32 + ty + 8*r) * 512 + by*32 + tx] = tile[tx][ty + 8*r];
  } else {
    const int bb = bid - 1280;
    const int tau = bb >> 4;
    const int b = (bb >> 2) & 3, ab = bb & 3;
    const float* P = tau ? skp : sqp;
    const float* W = tau ? Wk : Wq;
    float* O = tau ? wksk : wqsq;
    float* sv = shm;
    for (int i = t; i < 512; i += 256){
      float s = 0.f;
      #pragma unroll
      for (int g = 0; g < NS; g++) s += P[((long)b * NS + g) * 512 + i];
      sv[i] = s;
    }
    __syncthreads();
    const int a = ab * 128 + (t >> 1), half = t & 1;
    const float* Wr = W + (long)a * 512 + half * 256;
    const float* sp2 = sv + half * 256;
    float d = 0.f;
    #pragma unroll 8
    for (int j = 0; j < 256; j++) d += Wr[j] * sp2[j];
    d += __shfl_xor(d, 1);
    if (!half) O[(long)b * 512 + a] = d;
  }
}

__global__ __launch_bounds__(256) void softmax_k(
    const float* __restrict__ num, float* __restrict__ attn, float* __restrict__ cv,
    const float* __restrict__ wqsq, const float* __restrict__ wksk,
    const float* __restrict__ bq, const float* __restrict__ bk,
    const float* __restrict__ bv, const int* __restrict__ gt)
{
  const int a = blockIdx.x, b = blockIdx.y;
  const int t = threadIdx.x;
  const int lane = t & 63, wid = t >> 6;
  __shared__ unsigned char gf[512];
  __shared__ float red[4];
  gf[t] = 0; gf[t + 256] = 0;
  __syncthreads();
  if (t < 64) gf[gt[t]] = 1;
  __syncthreads();

  const float* row = num + ((long)b * 512 + a) * 512;
  const float bqa = bq[a], wqa = wqsq[b * 512 + a];
  const int ga = gf[a];
  const int c0 = t, c1 = t + 256;
  float l0 = (row[c0] + wqa * bk[c0] + bqa * wksk[b*512 + c0] + 8192.0f * bqa * bk[c0]) * 0.04419417382415922f;
  float l1 = (row[c1] + wqa * bk[c1] + bqa * wksk[b*512 + c1] + 8192.0f * bqa * bk[c1]) * 0.04419417382415922f;
  if (a < c0 && !ga && !gf[c0]) l0 = -1e30f;
  if (a < c1 && !ga && !gf[c1]) l1 = -1e30f;

  float m = fmaxf(l0, l1);
  #pragma unroll
  for (int o = 32; o; o >>= 1) m = fmaxf(m, __shfl_xor(m, o));
  if (lane == 0) red[wid] = m;
  __syncthreads();
  m = fmaxf(fmaxf(red[0], red[1]), fmaxf(red[2], red[3]));
  __syncthreads();

  float e0 = __expf(l0 - m), e1 = __expf(l1 - m);
  float s = e0 + e1;
  #pragma unroll
  for (int o = 32; o; o >>= 1) s += __shfl_xor(s, o);
  if (lane == 0) red[wid] = s;
  __syncthreads();
  s = red[0] + red[1] + red[2] + red[3];
  __syncthreads();
  const float inv = 1.0f / s;
  const float a0 = e0 * inv, a1 = e1 * inv;
  float* arow = attn + ((long)b * 512 + a) * 512;
  arow[c0] = a0; arow[c1] = a1;

  float cp = a0 * bv[c0] + a1 * bv[c1];
  #pragma unroll
  for (int o = 32; o; o >>= 1) cp += __shfl_xor(cp, o);
  if (lane == 0) red[wid] = cp;
  __syncthreads();
  if (t == 0) cv[(long)b * 512 + a] = red[0] + red[1] + red[2] + red[3];
}

// ---------------- launch -----------------------------------------------------
extern "C" void kernel_launch(void* const* d_in, const int* in_sizes, int n_in,
                              void* d_out, int out_size, void* d_ws, size_t ws_size,
                              hipStream_t stream) {
  const float* q  = (const float*)d_in[0];
  const float* k  = (const float*)d_in[1];
  const float* v  = (const float*)d_in[2];
  const float* Wq = (const float*)d_in[3];
  const float* bq = (const float*)d_in[4];
  const float* Wk = (const float*)d_in[5];
  const float* bk = (const float*)d_in[6];
  const float* Wv = (const float*)d_in[7];
  const float* bv = (const float*)d_in[8];
  const int*   gt = (const int*)d_in[9];
  float* out = (float*)d_out;

  float* w = (float*)d_ws;
  float* MT   = w;                          // slice 0 after in-place reduce
  float* T1   = w + 1048576;
  float* NUM  = w + 2097152;
  float* ATT  = w + 3145728;
  float* A2H  = w + 4194304;                // 524288 f32 = 1M ushorts
  float* WVT  = A2H + 524288;               // 262144
  float* SM   = w + 8L * 1048576;           // smalls past slice region
  float* SQP  = SM;
  float* SKP  = SQP + 32768;
  float* WQS  = SKP + 32768;
  float* WKS  = WQS + 2048;
  float* CV   = WKS + 2048;
  ushort_t* a2h = (ushort_t*)A2H;

  gemm1_tn<8><<<dim3(16, 8, 4), 256, 0, stream>>>(q, k, w, SQP, SKP);
  midprep<8><<<1312, 256, 0, stream>>>(w, Wv, WVT, SQP, SKP, Wq, Wk, WQS, WKS);
  // T1[a][j] = sum_i Wq[a][i] * MT[j][i]
  gemm_bt<64,0,0,3,0,0><<<dim3(64, 4), 256, 0, stream>>>(Wq, MT, T1, nullptr,
      8, 512, 512, 512, 512, 0L, 262144L, 262144L, 0L);
  // NUM[a][c] = sum_j T1[a][j] * Wk[c][j]
  gemm_bt<64,0,0,3,0,0><<<dim3(64, 4), 256, 0, stream>>>(T1, Wk, NUM, nullptr,
      8, 512, 512, 512, 512, 262144L, 0L, 262144L, 0L);
  softmax_k<<<dim3(512, 4), 256, 0, stream>>>(NUM, ATT, CV, WQS, WKS, bq, bk, bv, gt);
  // A2[a][i] = sum_c attn[a][c] * WvT[i][c] -> bf16
  gemm_bt<64,0,0,1,0,1><<<dim3(64, 4), 256, 0, stream>>>(ATT, WVT, a2h, nullptr,
      8, 512, 512, 512, 512, 262144L, 0L, 262144L, 0L);
  // out[a][s] = sum_i A2[a][i] * v[s][i] + cv[a]   (A bf16)
  gemm_bt<128,1,0,1,1,0><<<dim3(256, 4), 256, 0, stream>>>(a2h, v, out, CV,
      64, 512, 512, 512, 8192, 262144L, 4194304L, 4194304L, 512L);
}